// Round 13
// baseline (99.368 us; speedup 1.0000x reference)
//
#include <hip/hip_runtime.h>

// Problem constants (reference: shape (2,1,160,192,160), win=9)
#define BB 2
#define DD 160
#define HH 192
#define WW 160
#define HW (HH * WW)
#define PAD 4
#define TH 16
#define TW 32
#define EXTH 24             // TH + 2*PAD
#define EXTW 40             // TW + 2*PAD
#define XSTR 40             // sb row stride (words); 16B-aligned
#define APL 960             // per-array plane words (EXTH*XSTR)
#define WRS 36              // ws row stride (32 outs + 4 pad)
#define WCSTR 868           // ws channel stride; %32==4 (stagger), %4==0
#define HRS 36              // hs row stride
#define HCSTR 580           // hs channel stride; %32==4 (stagger), %4==0
#define CHUNK 19
#define NCH 9               // chunks: dc0 = 0,19,...,152 (last has 8 outputs)
#define NITER 27            // CHUNK + 2*PAD = 3*9 (static ring indexing)
#define WT (WW / TW)        // 5
#define HT (HH / TH)        // 12
#define NBLK (WT * HT * NCH * BB)   // 1080
#define NTASK 480           // staging float4 tasks: 2 arrays x 24 rows x 10 quads
#define EPS 1e-5f
#define INV_WS (1.0f / 729.0f)

// barrier that waits LDS only — never drains vmcnt (keeps prefetch in flight)
__device__ __forceinline__ void bar_lgkm() {
  asm volatile("s_waitcnt lgkmcnt(0)" ::: "memory");
  __builtin_amdgcn_s_barrier();
  asm volatile("" ::: "memory");
}

__device__ __forceinline__ float4 f4add(float4 a, float4 b) {
  return make_float4(a.x + b.x, a.y + b.y, a.z + b.z, a.w + b.w);
}
__device__ __forceinline__ float4 f4pm(float4 s, float4 p, float4 m) {
  return make_float4(s.x + p.x - m.x, s.y + p.y - m.y,
                     s.z + p.z - m.z, s.w + p.w - m.w);
}

__global__ void __launch_bounds__(256) k_lncc(
    const float* __restrict__ x, const float* __restrict__ y,
    float* __restrict__ partials)
{
  // Single-buffered; every RAW/WAR hazard crosses exactly one barrier:
  //   iter k = { P2(k) | barB | store(k+1)+prefetch(k+2)+P3(k) | barC | P4(k) }
  __shared__ __align__(16) float sb[2 * APL];     // x,y ext planes  7680 B
  __shared__ __align__(16) float ws[5 * WCSTR];   // W-filtered      17360 B
  __shared__ __align__(16) float hs[5 * HCSTR];   // W+H-filtered    11600 B
  __shared__ float red[4];

  const int t = threadIdx.x;
  const int w0 = blockIdx.x * TW;
  const int h0 = blockIdx.y * TH;
  const int bz = blockIdx.z;
  const int b = bz / NCH;
  const int chunk = bz - b * NCH;
  const int dc0 = chunk * CHUNK;
  const int g0 = dc0 - PAD;

  // ---- zero planes once (OOB slots stay 0 forever) ----
  for (int i = t; i < 2 * APL; i += 256) sb[i] = 0.f;

  // ---- staging descriptors: 480 float4 tasks; thread t gets t and t+256 ----
  int la0, la1; bool tk0, tk1;
  const float* gp0; const float* gp1;
  {
    const float* bx = x + (long)b * DD * HW;
    const float* by = y + (long)b * DD * HW;
#define MKTASK(TAU, LA, TK, GP)                                           \
    {                                                                     \
      int tau = (TAU);                                                    \
      int a = tau / 240;                                                  \
      int rem = tau - 240 * a;                                            \
      int r = rem / 10;                                                   \
      int q = rem - 10 * r;                                               \
      int aa = (a < 2) ? a : 0;                                           \
      int gh = h0 - PAD + r;                                              \
      int gw = w0 - PAD + 4 * q;                                          \
      bool ok = (tau < NTASK) && ((unsigned)gh < (unsigned)HH) &&         \
                ((unsigned)gw < (unsigned)WW);                            \
      LA = aa * APL + r * XSTR + 4 * q;                                   \
      TK = ok;                                                            \
      GP = (aa ? by : bx) + (ok ? (gh * WW + gw) : 0);                    \
    }
    MKTASK(t, la0, tk0, gp0)
    MKTASK(t + 256, la1, tk1, gp1)
#undef MKTASK
  }

  // ---- P2 constants (t<192): task = (ext row r2, quad qq) ----
  // one x,y row read (3+3 b128) serves all 5 channels (4 outputs each, b128)
  const int r2 = t >> 3;            // 0..23
  const int qq = t & 7;             // outputs w = 4qq..4qq+3
  const int rdx = r2 * XSTR + 4 * qq;   // x at [rdx..+11]; y at +APL
  const int wwr = r2 * WRS + 4 * qq;    // + c*WCSTR

  // ---- P3 constants (t<40): task = (channel c3, quad wq3), full column ----
  // 24 strided b128 reads (bank-floor), 16 sliding outputs, b128 writes
  const int c3 = t / 8, wq3 = t - 8 * c3;
  const int rb3 = c3 * WCSTR + 4 * wq3;   // + i*WRS, i=0..23
  const int wb3 = c3 * HCSTR + 4 * wq3;   // + h*HRS, h=0..15

  // ---- P4 constants: thread owns w-pair (2p4, 2p4+1) at row h4 ----
  const int h4 = t >> 4, p4 = t & 15;
  const int hrOff = h4 * HRS + 2 * p4;    // + c*HCSTR (float2)

  // ---- D-window ring: 9 deep x 5 ch x 2 outputs (static idx -> regs) ----
  float2 rg[9][5];
#pragma unroll
  for (int i = 0; i < 9; ++i)
#pragma unroll
    for (int c = 0; c < 5; ++c) { rg[i][c].x = 0.f; rg[i][c].y = 0.f; }
  float2 rn0 = {0, 0}, rn1 = {0, 0}, rn2 = {0, 0}, rn3 = {0, 0}, rn4 = {0, 0};
  float acc = 0.f;

  __syncthreads();   // zero-init visible

  // ---- prologue: store slice 0 directly; prefetch slice 1 into regs ----
  float4 st0 = make_float4(0, 0, 0, 0), st1 = st0;
  bool ps0 = false, ps1 = false;
  {
    if ((unsigned)g0 < (unsigned)DD) {
      const long so = (long)g0 * HW;
      if (tk0) *(float4*)&sb[la0] = *(const float4*)(gp0 + so);
      if (tk1) *(float4*)&sb[la1] = *(const float4*)(gp1 + so);
    }
    const int g1i = g0 + 1;
    const bool v1 = ((unsigned)g1i < (unsigned)DD);
    const long so1 = (long)g1i * HW;
    ps0 = tk0 && v1; if (ps0) st0 = *(const float4*)(gp0 + so1);
    ps1 = tk1 && v1; if (ps1) st1 = *(const float4*)(gp1 + so1);
  }
  __syncthreads();   // slice-0 stores visible

  for (int ko = 0; ko < 3; ++ko) {
#pragma unroll
    for (int jj = 0; jj < 9; ++jj) {
      const int k = ko * 9 + jj;
      const int g = g0 + k;
      const bool gv = ((unsigned)g < (unsigned)DD);   // block-uniform

      // ---- P2(k): W-filter; reads sb, writes ws ----
      if (gv && t < 192) {
        float xa[12], ya[12];
        {
          float4 X0 = *(const float4*)&sb[rdx];
          float4 X1 = *(const float4*)&sb[rdx + 4];
          float4 X2 = *(const float4*)&sb[rdx + 8];
          xa[0]=X0.x; xa[1]=X0.y; xa[2]=X0.z; xa[3]=X0.w;
          xa[4]=X1.x; xa[5]=X1.y; xa[6]=X1.z; xa[7]=X1.w;
          xa[8]=X2.x; xa[9]=X2.y; xa[10]=X2.z; xa[11]=X2.w;
          float4 Y0 = *(const float4*)&sb[APL + rdx];
          float4 Y1 = *(const float4*)&sb[APL + rdx + 4];
          float4 Y2 = *(const float4*)&sb[APL + rdx + 8];
          ya[0]=Y0.x; ya[1]=Y0.y; ya[2]=Y0.z; ya[3]=Y0.w;
          ya[4]=Y1.x; ya[5]=Y1.y; ya[6]=Y1.z; ya[7]=Y1.w;
          ya[8]=Y2.x; ya[9]=Y2.y; ya[10]=Y2.z; ya[11]=Y2.w;
        }
#define EMITCH(CIDX, EXPR)                                                 \
        {                                                                  \
          float qv[12];                                                    \
          _Pragma("unroll")                                                \
          for (int i = 0; i < 12; ++i) qv[i] = (EXPR);                     \
          float o0 = ((qv[0]+qv[1])+(qv[2]+qv[3]))+                        \
                     ((qv[4]+qv[5])+(qv[6]+qv[7]))+qv[8];                  \
          float o1 = o0 + qv[9]  - qv[0];                                  \
          float o2 = o1 + qv[10] - qv[1];                                  \
          float o3 = o2 + qv[11] - qv[2];                                  \
          *(float4*)&ws[(CIDX) * WCSTR + wwr] = make_float4(o0,o1,o2,o3);  \
        }
        EMITCH(0, xa[i])
        EMITCH(1, ya[i])
        EMITCH(2, xa[i] * xa[i])
        EMITCH(3, ya[i] * ya[i])
        EMITCH(4, xa[i] * ya[i])
#undef EMITCH
      }

      bar_lgkm();  // B: P2's sb reads done -> store(k+1) WAR-safe;
                   //    ws writes visible for P3

      // ---- store slice k+1 -> sb (overlaps P3) ----
      if (ps0) *(float4*)&sb[la0] = st0;
      if (ps1) *(float4*)&sb[la1] = st1;

      // ---- prefetch slice k+2 into regs (in flight across barriers) ----
      {
        const int gn = g + 2;
        const bool nv = (k + 2 < NITER) && ((unsigned)gn < (unsigned)DD);
        const long so = (long)gn * HW;
        ps0 = tk0 && nv; if (ps0) st0 = *(const float4*)(gp0 + so);
        ps1 = tk1 && nv; if (ps1) st1 = *(const float4*)(gp1 + so);
      }

      // ---- P3(k): H-filter; full-column sliding (40 tasks) ----
      if (gv && t < 40) {
        float4 v[24];
#pragma unroll
        for (int i = 0; i < 9; ++i) v[i] = *(const float4*)&ws[rb3 + i * WRS];
        float4 s = f4add(f4add(f4add(f4add(v[0], v[1]), f4add(v[2], v[3])),
                               f4add(f4add(v[4], v[5]), f4add(v[6], v[7]))),
                         v[8]);
        *(float4*)&hs[wb3] = s;
#pragma unroll
        for (int hh = 1; hh < TH; ++hh) {
          v[hh + 8] = *(const float4*)&ws[rb3 + (hh + 8) * WRS];
          s = f4pm(s, v[hh + 8], v[hh - 1]);
          *(float4*)&hs[wb3 + hh * HRS] = s;
        }
      }

      bar_lgkm();  // C: hs visible for P4; sb store visible for next P2;
                   //    P3's ws reads done -> next P2's ws writes WAR-safe

      // ---- P4(k): channel reads + ring + cc ----
      float2 hv0 = {0, 0}, hv1 = {0, 0}, hv2 = {0, 0},
             hv3 = {0, 0}, hv4 = {0, 0};
      if (gv) {
        hv0 = *(const float2*)&hs[hrOff];
        hv1 = *(const float2*)&hs[HCSTR + hrOff];
        hv2 = *(const float2*)&hs[2 * HCSTR + hrOff];
        hv3 = *(const float2*)&hs[3 * HCSTR + hrOff];
        hv4 = *(const float2*)&hs[4 * HCSTR + hrOff];
        // P4 reads finish before barB(k+1) -> P3(k+1) hs writes WAR-safe
      }

      rn0.x += hv0.x - rg[jj][0].x; rg[jj][0].x = hv0.x;
      rn0.y += hv0.y - rg[jj][0].y; rg[jj][0].y = hv0.y;
      rn1.x += hv1.x - rg[jj][1].x; rg[jj][1].x = hv1.x;
      rn1.y += hv1.y - rg[jj][1].y; rg[jj][1].y = hv1.y;
      rn2.x += hv2.x - rg[jj][2].x; rg[jj][2].x = hv2.x;
      rn2.y += hv2.y - rg[jj][2].y; rg[jj][2].y = hv2.y;
      rn3.x += hv3.x - rg[jj][3].x; rg[jj][3].x = hv3.x;
      rn3.y += hv3.y - rg[jj][3].y; rg[jj][3].y = hv3.y;
      rn4.x += hv4.x - rg[jj][4].x; rg[jj][4].x = hv4.x;
      rn4.y += hv4.y - rg[jj][4].y; rg[jj][4].y = hv4.y;

      if (k >= 8) {
        const int d = dc0 + (k - 8);
        if (d < DD) {                 // block-uniform tail guard
          {
            float cross = fmaf(-rn0.x * INV_WS, rn1.x, rn4.x);
            float xv = fmaxf(fmaf(-rn0.x * INV_WS, rn0.x, rn2.x), EPS);
            float yv = fmaxf(fmaf(-rn1.x * INV_WS, rn1.x, rn3.x), EPS);
            acc += (cross * cross) * __builtin_amdgcn_rcpf(xv * yv);
          }
          {
            float cross = fmaf(-rn0.y * INV_WS, rn1.y, rn4.y);
            float xv = fmaxf(fmaf(-rn0.y * INV_WS, rn0.y, rn2.y), EPS);
            float yv = fmaxf(fmaf(-rn1.y * INV_WS, rn1.y, rn3.y), EPS);
            acc += (cross * cross) * __builtin_amdgcn_rcpf(xv * yv);
          }
        }
      }
    }
  }

  // ---- block reduction ----
#pragma unroll
  for (int o = 32; o > 0; o >>= 1) acc += __shfl_down(acc, o);
  if ((t & 63) == 0) red[t >> 6] = acc;
  __syncthreads();
  if (t == 0) {
    int bid = (bz * HT + blockIdx.y) * WT + blockIdx.x;
    partials[bid] = (red[0] + red[1]) + (red[2] + red[3]);
  }
}

__global__ void __launch_bounds__(256) k_finalize(
    const float* __restrict__ partials, float* __restrict__ out)
{
  __shared__ double red[256];
  double s = 0.0;
  for (int i = threadIdx.x; i < NBLK; i += 256) s += (double)partials[i];
  red[threadIdx.x] = s;
  __syncthreads();
  for (int o = 128; o > 0; o >>= 1) {
    if (threadIdx.x < o) red[threadIdx.x] += red[threadIdx.x + o];
    __syncthreads();
  }
  if (threadIdx.x == 0) {
    const double Nvox = (double)BB * DD * HH * WW;
    out[0] = (float)(-red[0] / Nvox);
  }
}

extern "C" void kernel_launch(void* const* d_in, const int* in_sizes, int n_in,
                              void* d_out, int out_size, void* d_ws, size_t ws_size,
                              hipStream_t stream) {
  (void)in_sizes; (void)n_in; (void)out_size; (void)ws_size;
  const float* x = (const float*)d_in[0];
  const float* y = (const float*)d_in[1];
  float* out = (float*)d_out;
  float* partials = (float*)d_ws;

  dim3 grid(WT, HT, BB * NCH);
  k_lncc<<<grid, 256, 0, stream>>>(x, y, partials);
  k_finalize<<<1, 256, 0, stream>>>(partials, out);
}

// Round 14
// 94.328 us; speedup vs baseline: 1.0534x; 1.0534x over previous
//
#include <hip/hip_runtime.h>

// Problem constants (reference: shape (2,1,160,192,160), win=9)
#define BB 2
#define DD 160
#define HH 192
#define WW 160
#define HW (HH * WW)
#define PAD 4
#define TH 16
#define TW 16
#define EXT 24              // TH+2*PAD == TW+2*PAD
#define XSTR 28             // plane row stride (words; rows 16B-aligned)
#define PLANE 768           // words per array plane (>= EXT*XSTR=672)
#define WCS 456             // wsum channel stride
#define WJS 28              // wsum j(col) stride (r contiguous, 16B-aligned)
#define HCS 272             // hsum channel stride
#define HHS 17              // hsum row stride (odd -> staggered)
#define CHUNK 19
#define NCH 9               // chunks: dc0 = 0,19,...,152 (last has 8 outputs)
#define NITER 27            // CHUNK + 2*PAD = 3*9 (static ring indexing)
#define WT (WW / TW)        // 10
#define HT (HH / TH)        // 12
#define NBLK (WT * HT * NCH * BB)  // 2160
#define NTASK 288           // staging float4 tasks per slice (2 arr x 24 r x 6 q)
#define EPS 1e-5f
#define INV_WS (1.0f / 729.0f)

// barrier that waits LDS only — never drains vmcnt (keeps prefetch in flight)
__device__ __forceinline__ void bar_lgkm() {
  asm volatile("s_waitcnt lgkmcnt(0)" ::: "memory");
  __builtin_amdgcn_s_barrier();
  asm volatile("" ::: "memory");
}

__global__ void __launch_bounds__(256) k_lncc(
    const float* __restrict__ x, const float* __restrict__ y,
    float* __restrict__ partials)
{
  // Single-buffered; every RAW/WAR hazard crosses exactly one barrier:
  //   iter k = { P2(k) | barB | store(k+1)+prefetch(k+2)+P3(k) | barC | P4(k) }
  __shared__ __align__(16) float sbuf[2][PLANE];     // [arr] x,y   6144 B
  __shared__ __align__(16) float ones[32];
  __shared__ __align__(16) float wsum[5 * WCS];      // 9120 B  [c][j][r]
  __shared__ __align__(16) float hsum[5 * HCS];      // 5440 B  [c][h*HHS+w]
  __shared__ float red[4];

  const int t = threadIdx.x;
  const int w0 = blockIdx.x * TW;
  const int h0 = blockIdx.y * TH;
  const int bz = blockIdx.z;
  const int b = bz / NCH;
  const int chunk = bz - b * NCH;
  const int dc0 = chunk * CHUNK;
  const int g0 = dc0 - PAD;

  // ---- init: zero planes (OOB slots stay 0 forever); ones row ----
  for (int i = t; i < 2 * PLANE; i += 256) (&sbuf[0][0])[i] = 0.f;
  if (t < 32) ones[t] = 1.0f;

  // ---- staging descriptors: NTASK float4 tasks; thread t gets t, 256+t ----
  int la0, la1; bool tk0, tk1;
  const float* gp0; const float* gp1;
  {
    const float* bx = x + (long)b * DD * HW;
    const float* by = y + (long)b * DD * HW;
#define MKTASK(TAU, LA, TK, GP)                                           \
    {                                                                     \
      int tau = (TAU);                                                    \
      int a = tau / 144;                                                  \
      int rem = tau - 144 * a;                                            \
      int r = rem / 6;                                                    \
      int q = rem - 6 * r;                                                \
      int aa = (a < 2) ? a : 0;                                           \
      int gh = h0 - PAD + r;                                              \
      int gw = w0 - PAD + 4 * q;                                          \
      bool ok = (tau < NTASK) && ((unsigned)gh < (unsigned)HH) &&         \
                ((unsigned)gw < (unsigned)WW);                            \
      LA = aa * PLANE + r * XSTR + 4 * q;                                 \
      TK = ok;                                                            \
      GP = (aa ? by : bx) + (ok ? (gh * WW + gw) : 0);                    \
    }
    MKTASK(t, la0, tk0, gp0)
    MKTASK(256 + t, la1, tk1, gp1)
#undef MKTASK
  }

  // ---- P2 constants (t<120): task = (channel c2, ext row r2) ----
  const int c2 = t / 24, r2 = t - c2 * 24;
  const int arrA = ((c2 == 1) || (c2 == 3)) ? 1 : 0;
  const int arrB = (c2 == 2) ? 0 : 1;
  const bool useOnes = (c2 < 2);
  const int paOff = arrA * PLANE + r2 * XSTR;
  const int pbOff = arrB * PLANE + r2 * XSTR;
  float* const wwr = &wsum[c2 * WCS + r2];      // + j*WJS

  // ---- P3 constants (t<80): task = (channel c3, out col w3) ----
  const int c3 = t / 16, w3 = t - c3 * 16;
  const float* const wrd = &wsum[c3 * WCS + w3 * WJS];  // + i contiguous
  float* const hwr = &hsum[c3 * HCS + w3];              // + h*HHS

  // ---- P4 constants: one output (h,w) per thread ----
  const int h4 = t >> 4, w4 = t & 15;
  const float* const hrd = &hsum[h4 * HHS + w4];        // + c*HCS

  // ---- D-window ring (static idx via jj), running sums ----
  float ring[9][5];
#pragma unroll
  for (int i = 0; i < 9; ++i)
#pragma unroll
    for (int c = 0; c < 5; ++c) ring[i][c] = 0.f;
  float run0 = 0.f, run1 = 0.f, run2 = 0.f, run3 = 0.f, run4 = 0.f, acc = 0.f;

  __syncthreads();   // zero-init visible before any staging store

  // ---- prologue: store slice 0 directly; prefetch slice 1 into regs ----
  float4 st0 = make_float4(0, 0, 0, 0), st1 = st0;
  bool ps0 = false, ps1 = false;
  {
    if ((unsigned)g0 < (unsigned)DD) {
      const long so = (long)g0 * HW;
      if (tk0) *(float4*)&sbuf[0][la0] = *(const float4*)(gp0 + so);
      if (tk1) *(float4*)&sbuf[0][la1] = *(const float4*)(gp1 + so);
    }
    const int g1i = g0 + 1;
    const bool v1 = ((unsigned)g1i < (unsigned)DD);
    const long so1 = (long)g1i * HW;
    ps0 = tk0 && v1; if (ps0) st0 = *(const float4*)(gp0 + so1);
    ps1 = tk1 && v1; if (ps1) st1 = *(const float4*)(gp1 + so1);
  }
  __syncthreads();   // slice-0 stores visible

  for (int ko = 0; ko < 3; ++ko) {
#pragma unroll
    for (int jj = 0; jj < 9; ++jj) {
      const int k = ko * 9 + jj;
      const int g = g0 + k;
      const bool gv = ((unsigned)g < (unsigned)DD);  // block-uniform

      // ---- P2(k): W-filter; tree-structured 9-sums (depth 4, no chain) ----
      if (gv && t < 120) {
        const float* pa = &sbuf[0][0] + paOff;
        const float* pb = useOnes ? &ones[0] : (&sbuf[0][0] + pbOff);
        float4 A0 = *(const float4*)(pa);
        float4 A1 = *(const float4*)(pa + 4);
        float4 A2 = *(const float4*)(pa + 8);
        float4 A3 = *(const float4*)(pa + 12);
        float4 A4 = *(const float4*)(pa + 16);
        float4 A5 = *(const float4*)(pa + 20);
        float4 B0 = *(const float4*)(pb);
        float4 B1 = *(const float4*)(pb + (useOnes ? 0 : 4));
        float4 B2 = *(const float4*)(pb + (useOnes ? 0 : 8));
        float4 B3 = *(const float4*)(pb + (useOnes ? 0 : 12));
        float4 B4 = *(const float4*)(pb + (useOnes ? 0 : 16));
        float4 B5 = *(const float4*)(pb + (useOnes ? 0 : 20));
        float q[EXT];
        q[0]=A0.x*B0.x; q[1]=A0.y*B0.y; q[2]=A0.z*B0.z; q[3]=A0.w*B0.w;
        q[4]=A1.x*B1.x; q[5]=A1.y*B1.y; q[6]=A1.z*B1.z; q[7]=A1.w*B1.w;
        q[8]=A2.x*B2.x; q[9]=A2.y*B2.y; q[10]=A2.z*B2.z; q[11]=A2.w*B2.w;
        q[12]=A3.x*B3.x; q[13]=A3.y*B3.y; q[14]=A3.z*B3.z; q[15]=A3.w*B3.w;
        q[16]=A4.x*B4.x; q[17]=A4.y*B4.y; q[18]=A4.z*B4.z; q[19]=A4.w*B4.w;
        q[20]=A5.x*B5.x; q[21]=A5.y*B5.y; q[22]=A5.z*B5.z; q[23]=A5.w*B5.w;
        float s2[23];
#pragma unroll
        for (int i = 0; i < 23; ++i) s2[i] = q[i] + q[i + 1];
        float s4[21];
#pragma unroll
        for (int i = 0; i < 21; ++i) s4[i] = s2[i] + s2[i + 2];
#pragma unroll
        for (int j = 0; j < TW; ++j)
          wwr[j * WJS] = (s4[j] + s4[j + 4]) + q[j + 8];
      }

      bar_lgkm();  // B: P2's sbuf reads done -> store(k+1) WAR-safe;
                   //    wsum writes visible for P3

      // ---- store slice k+1 -> sbuf (overlaps P3) ----
      if (ps0) *(float4*)&sbuf[0][la0] = st0;
      if (ps1) *(float4*)&sbuf[0][la1] = st1;

      // ---- prefetch slice k+2 into regs (in flight across barriers) ----
      {
        const int gn = g + 2;
        const bool nv = (k + 2 < NITER) && ((unsigned)gn < (unsigned)DD);
        const long so = (long)gn * HW;
        ps0 = tk0 && nv; if (ps0) st0 = *(const float4*)(gp0 + so);
        ps1 = tk1 && nv; if (ps1) st1 = *(const float4*)(gp1 + so);
      }

      // ---- P3(k): H-filter; tree-structured 9-sums ----
      if (gv && t < 80) {
        float4 V0 = *(const float4*)(wrd);
        float4 V1 = *(const float4*)(wrd + 4);
        float4 V2 = *(const float4*)(wrd + 8);
        float4 V3 = *(const float4*)(wrd + 12);
        float4 V4 = *(const float4*)(wrd + 16);
        float4 V5 = *(const float4*)(wrd + 20);
        float v[EXT];
        v[0]=V0.x; v[1]=V0.y; v[2]=V0.z; v[3]=V0.w;
        v[4]=V1.x; v[5]=V1.y; v[6]=V1.z; v[7]=V1.w;
        v[8]=V2.x; v[9]=V2.y; v[10]=V2.z; v[11]=V2.w;
        v[12]=V3.x; v[13]=V3.y; v[14]=V3.z; v[15]=V3.w;
        v[16]=V4.x; v[17]=V4.y; v[18]=V4.z; v[19]=V4.w;
        v[20]=V5.x; v[21]=V5.y; v[22]=V5.z; v[23]=V5.w;
        float u2[23];
#pragma unroll
        for (int i = 0; i < 23; ++i) u2[i] = v[i] + v[i + 1];
        float u4[21];
#pragma unroll
        for (int i = 0; i < 21; ++i) u4[i] = u2[i] + u2[i + 2];
#pragma unroll
        for (int h = 0; h < TH; ++h)
          hwr[h * HHS] = (u4[h] + u4[h + 4]) + v[h + 8];
      }

      bar_lgkm();  // C: hsum visible for P4; sbuf store visible for next P2;
                   //    P3's wsum reads done -> next P2's wsum writes WAR-safe

      // ---- P4(k): per-output channel reads + ring + cc ----
      float hv0 = 0.f, hv1 = 0.f, hv2 = 0.f, hv3 = 0.f, hv4 = 0.f;
      if (gv) {
        hv0 = hrd[0];
        hv1 = hrd[HCS];
        hv2 = hrd[2 * HCS];
        hv3 = hrd[3 * HCS];
        hv4 = hrd[4 * HCS];
        // P4 reads complete before barB(k+1) -> P3(k+1) hsum writes WAR-safe
      }

      run0 += hv0 - ring[jj][0]; ring[jj][0] = hv0;
      run1 += hv1 - ring[jj][1]; ring[jj][1] = hv1;
      run2 += hv2 - ring[jj][2]; ring[jj][2] = hv2;
      run3 += hv3 - ring[jj][3]; ring[jj][3] = hv3;
      run4 += hv4 - ring[jj][4]; ring[jj][4] = hv4;

      if (k >= 8) {
        const int d = dc0 + (k - 8);
        if (d < DD) {                   // block-uniform tail guard
          float cross = fmaf(-run0 * INV_WS, run1, run4);
          float xv = fmaxf(fmaf(-run0 * INV_WS, run0, run2), EPS);
          float yv = fmaxf(fmaf(-run1 * INV_WS, run1, run3), EPS);
          acc += (cross * cross) * __builtin_amdgcn_rcpf(xv * yv);
        }
      }
    }
  }

  // ---- block reduction ----
#pragma unroll
  for (int o = 32; o > 0; o >>= 1) acc += __shfl_down(acc, o);
  if ((t & 63) == 0) red[t >> 6] = acc;
  __syncthreads();
  if (t == 0) {
    int bid = (bz * HT + blockIdx.y) * WT + blockIdx.x;
    partials[bid] = (red[0] + red[1]) + (red[2] + red[3]);
  }
}

__global__ void __launch_bounds__(256) k_finalize(
    const float* __restrict__ partials, float* __restrict__ out)
{
  __shared__ double red[256];
  double s = 0.0;
  for (int i = threadIdx.x; i < NBLK; i += 256) s += (double)partials[i];
  red[threadIdx.x] = s;
  __syncthreads();
  for (int o = 128; o > 0; o >>= 1) {
    if (threadIdx.x < o) red[threadIdx.x] += red[threadIdx.x + o];
    __syncthreads();
  }
  if (threadIdx.x == 0) {
    const double Nvox = (double)BB * DD * HH * WW;
    out[0] = (float)(-red[0] / Nvox);
  }
}

extern "C" void kernel_launch(void* const* d_in, const int* in_sizes, int n_in,
                              void* d_out, int out_size, void* d_ws, size_t ws_size,
                              hipStream_t stream) {
  (void)in_sizes; (void)n_in; (void)out_size; (void)ws_size;
  const float* x = (const float*)d_in[0];
  const float* y = (const float*)d_in[1];
  float* out = (float*)d_out;
  float* partials = (float*)d_ws;

  dim3 grid(WT, HT, BB * NCH);
  k_lncc<<<grid, 256, 0, stream>>>(x, y, partials);
  k_finalize<<<1, 256, 0, stream>>>(partials, out);
}

// Round 15
// 76.165 us; speedup vs baseline: 1.3047x; 1.2385x over previous
//
#include <hip/hip_runtime.h>

// Problem constants (reference: shape (2,1,160,192,160), win=9)
#define BB 2
#define DD 160
#define HH 192
#define WW 160
#define HW (HH * WW)
#define PAD 4
#define TH 16
#define TW 16
#define EXT 24              // TH+2*PAD == TW+2*PAD
#define XSTR 28             // plane row stride (words; rows 16B-aligned)
#define PLANE 768           // words per array plane (>= EXT*XSTR=672)
#define WCS 456             // wsum channel stride
#define WJS 28              // wsum j(col) stride (r contiguous, 16B-aligned)
#define WPS (5 * WCS)       // wsum slice-parity stride (2280)
#define HCS 272             // hsum channel stride
#define HHS 17              // hsum row stride (odd -> staggered)
#define CHUNK 28
#define NCH 6               // ceil(DD/CHUNK)
#define NITER 36            // slices 0..35; CHUNK + 2*PAD = 4*9
#define WT (WW / TW)        // 10
#define HT (HH / TH)        // 12
#define NBLK (WT * HT * NCH * BB)  // 1440
#define NTASK 288           // staging float4 tasks per slice (2 arr x 24 r x 6 q)
#define EPS 1e-5f
#define INV_WS (1.0f / 729.0f)

// barrier that waits LDS only — never drains vmcnt (keeps prefetch in flight)
__device__ __forceinline__ void bar_lgkm() {
  asm volatile("s_waitcnt lgkmcnt(0)" ::: "memory");
  __builtin_amdgcn_s_barrier();
  asm volatile("" ::: "memory");
}

__global__ void __launch_bounds__(256) k_lncc(
    const float* __restrict__ x, const float* __restrict__ y,
    float* __restrict__ partials)
{
  // Wave-specialized pipeline. Per slice m (loop iter):
  //   I1: waves 0-1: P2(m) -> wsum[m&1]   ||  waves 2-3: P3(m-1) <- wsum[(m-1)&1]
  //   barB
  //   I2: P4(m-1) <- hsum; store slice m+1 -> sbuf; prefetch m+2
  //   barC
  // Hazards: sbuf store(m+1 in I2) vs P2(m) reads(I1): crosses barB; vs P2(m+1)
  // reads: crosses barC. wsum parities disjoint in I1; P2(m) write vs P3(m)
  // read crosses barB+barC. hsum: P3(m-1) write (I1) vs P4(m-1) read (I2)
  // crosses barB; P4(m-1) read vs P3(m) write (next I1) crosses barC.
  __shared__ __align__(16) float sbuf[2][PLANE];     // [arr] x,y   6144 B
  __shared__ __align__(16) float ones[32];
  __shared__ __align__(16) float wsum[2 * WPS];      // 18240 B [par][c][j][r]
  __shared__ __align__(16) float hsum[5 * HCS];      // 5440 B  [c][h*HHS+w]
  __shared__ float red[4];

  const int t = threadIdx.x;
  const int w0 = blockIdx.x * TW;
  const int h0 = blockIdx.y * TH;
  const int bz = blockIdx.z;
  const int b = bz / NCH;
  const int chunk = bz - b * NCH;
  const int dc0 = chunk * CHUNK;
  const int g0 = dc0 - PAD;

  // ---- init: zero planes (OOB slots stay 0 forever); ones row ----
  for (int i = t; i < 2 * PLANE; i += 256) (&sbuf[0][0])[i] = 0.f;
  if (t < 32) ones[t] = 1.0f;

  // ---- staging descriptors: NTASK float4 tasks; thread t gets t, 256+t ----
  int la0, la1; bool tk0, tk1;
  const float* gp0; const float* gp1;
  {
    const float* bx = x + (long)b * DD * HW;
    const float* by = y + (long)b * DD * HW;
#define MKTASK(TAU, LA, TK, GP)                                           \
    {                                                                     \
      int tau = (TAU);                                                    \
      int a = tau / 144;                                                  \
      int rem = tau - 144 * a;                                            \
      int r = rem / 6;                                                    \
      int q = rem - 6 * r;                                                \
      int aa = (a < 2) ? a : 0;                                           \
      int gh = h0 - PAD + r;                                              \
      int gw = w0 - PAD + 4 * q;                                          \
      bool ok = (tau < NTASK) && ((unsigned)gh < (unsigned)HH) &&         \
                ((unsigned)gw < (unsigned)WW);                            \
      LA = aa * PLANE + r * XSTR + 4 * q;                                 \
      TK = ok;                                                            \
      GP = (aa ? by : bx) + (ok ? (gh * WW + gw) : 0);                    \
    }
    MKTASK(t, la0, tk0, gp0)
    MKTASK(256 + t, la1, tk1, gp1)
#undef MKTASK
  }

  // ---- P2 constants (waves 0-1; task valid t<120): (channel c2, row r2) ----
  const int c2 = t / 24, r2 = t - c2 * 24;
  const int arrA = ((c2 == 1) || (c2 == 3)) ? 1 : 0;
  const int arrB = (c2 == 2) ? 0 : 1;
  const bool useOnes = (c2 < 2);
  const int paOff = arrA * PLANE + r2 * XSTR;
  const int pbOff = arrB * PLANE + r2 * XSTR;
  const int wwOff = c2 * WCS + r2;              // + par*WPS + j*WJS

  // ---- P3 constants (waves 2-3; task tt=t-128 valid <80): (c3, w3) ----
  const int tt = t - 128;
  const int c3 = (tt >= 0 ? tt : 0) / 16, w3 = (tt >= 0 ? tt : 0) & 15;
  const int wrOff = c3 * WCS + w3 * WJS;        // + par*WPS, i contiguous
  float* const hwr = &hsum[c3 * HCS + w3];      // + h*HHS

  // ---- P4 constants: one output (h,w) per thread ----
  const int h4 = t >> 4, w4 = t & 15;
  const float* const hrd = &hsum[h4 * HHS + w4];  // + c*HCS

  // ---- D-window ring (static idx via jj), running sums ----
  float ring[9][5];
#pragma unroll
  for (int i = 0; i < 9; ++i)
#pragma unroll
    for (int c = 0; c < 5; ++c) ring[i][c] = 0.f;
  float run0 = 0.f, run1 = 0.f, run2 = 0.f, run3 = 0.f, run4 = 0.f, acc = 0.f;

  __syncthreads();   // zero-init visible

// P2 body: reads sbuf rows, writes wsum[par] at wwOff (sliding recurrence)
#define P2_BODY(PARBASE)                                                   \
  {                                                                        \
    const float* pa = &sbuf[0][0] + paOff;                                 \
    const float* pb = useOnes ? &ones[0] : (&sbuf[0][0] + pbOff);          \
    float4 A0 = *(const float4*)(pa);                                      \
    float4 A1 = *(const float4*)(pa + 4);                                  \
    float4 A2 = *(const float4*)(pa + 8);                                  \
    float4 A3 = *(const float4*)(pa + 12);                                 \
    float4 A4 = *(const float4*)(pa + 16);                                 \
    float4 A5 = *(const float4*)(pa + 20);                                 \
    float4 B0 = *(const float4*)(pb);                                      \
    float4 B1 = *(const float4*)(pb + (useOnes ? 0 : 4));                  \
    float4 B2 = *(const float4*)(pb + (useOnes ? 0 : 8));                  \
    float4 B3 = *(const float4*)(pb + (useOnes ? 0 : 12));                 \
    float4 B4 = *(const float4*)(pb + (useOnes ? 0 : 16));                 \
    float4 B5 = *(const float4*)(pb + (useOnes ? 0 : 20));                 \
    float q[EXT];                                                          \
    q[0]=A0.x*B0.x; q[1]=A0.y*B0.y; q[2]=A0.z*B0.z; q[3]=A0.w*B0.w;        \
    q[4]=A1.x*B1.x; q[5]=A1.y*B1.y; q[6]=A1.z*B1.z; q[7]=A1.w*B1.w;        \
    q[8]=A2.x*B2.x; q[9]=A2.y*B2.y; q[10]=A2.z*B2.z; q[11]=A2.w*B2.w;      \
    q[12]=A3.x*B3.x; q[13]=A3.y*B3.y; q[14]=A3.z*B3.z; q[15]=A3.w*B3.w;    \
    q[16]=A4.x*B4.x; q[17]=A4.y*B4.y; q[18]=A4.z*B4.z; q[19]=A4.w*B4.w;    \
    q[20]=A5.x*B5.x; q[21]=A5.y*B5.y; q[22]=A5.z*B5.z; q[23]=A5.w*B5.w;    \
    float s = ((q[0] + q[1]) + (q[2] + q[3])) +                            \
              ((q[4] + q[5]) + (q[6] + q[7])) + q[8];                      \
    float* wq = &wsum[(PARBASE) + wwOff];                                  \
    wq[0] = s;                                                             \
    _Pragma("unroll")                                                      \
    for (int j = 1; j < TW; ++j) {                                         \
      s += q[j + 8] - q[j - 1];                                            \
      wq[j * WJS] = s;                                                     \
    }                                                                      \
  }

  // ---- prologue ----
  float4 st0 = make_float4(0, 0, 0, 0), st1 = st0;
  bool ps0 = false, ps1 = false;
  {
    // direct-store slice 0; prefetch slice 1
    if ((unsigned)g0 < (unsigned)DD) {
      const long so = (long)g0 * HW;
      if (tk0) *(float4*)&(&sbuf[0][0])[la0] = *(const float4*)(gp0 + so);
      if (tk1) *(float4*)&(&sbuf[0][0])[la1] = *(const float4*)(gp1 + so);
    }
    const int g1i = g0 + 1;
    const bool v1 = ((unsigned)g1i < (unsigned)DD);
    const long so1 = (long)g1i * HW;
    ps0 = tk0 && v1; if (ps0) st0 = *(const float4*)(gp0 + so1);
    ps1 = tk1 && v1; if (ps1) st1 = *(const float4*)(gp1 + so1);
  }
  __syncthreads();   // slice-0 stores visible
  // P2(0) -> wsum[par 0]
  if (((unsigned)g0 < (unsigned)DD) && t < 120) P2_BODY(0)
  bar_lgkm();        // P2(0)'s sbuf reads done -> store slice 1 safe
  if (ps0) *(float4*)&(&sbuf[0][0])[la0] = st0;
  if (ps1) *(float4*)&(&sbuf[0][0])[la1] = st1;
  {
    const int gn = g0 + 2;
    const bool nv = (2 < NITER) && ((unsigned)gn < (unsigned)DD);
    const long so = (long)gn * HW;
    ps0 = tk0 && nv; if (ps0) st0 = *(const float4*)(gp0 + so);
    ps1 = tk1 && nv; if (ps1) st1 = *(const float4*)(gp1 + so);
  }
  bar_lgkm();        // slice-1 stores visible for P2(1)

  // ---- main loop: m = 1..36 ----
  for (int ko = 0; ko < 4; ++ko) {
#pragma unroll
    for (int jj = 0; jj < 9; ++jj) {
      const int m = ko * 9 + jj + 1;
      const int s = m - 1;               // P3/P4 slice; s % 9 == jj

      // ---- I1: P2(m) on waves 0-1  ||  P3(s) on waves 2-3 ----
      if (t < 128) {
        if ((m < NITER) && ((unsigned)(g0 + m) < (unsigned)DD) && (t < 120))
          P2_BODY((m & 1) * WPS)
      } else {
        if (((unsigned)(g0 + s) < (unsigned)DD) && (tt < 80)) {
          const float* wrd = &wsum[(s & 1) * WPS + wrOff];
          float4 V0 = *(const float4*)(wrd);
          float4 V1 = *(const float4*)(wrd + 4);
          float4 V2 = *(const float4*)(wrd + 8);
          float4 V3 = *(const float4*)(wrd + 12);
          float4 V4 = *(const float4*)(wrd + 16);
          float4 V5 = *(const float4*)(wrd + 20);
          float v[EXT];
          v[0]=V0.x; v[1]=V0.y; v[2]=V0.z; v[3]=V0.w;
          v[4]=V1.x; v[5]=V1.y; v[6]=V1.z; v[7]=V1.w;
          v[8]=V2.x; v[9]=V2.y; v[10]=V2.z; v[11]=V2.w;
          v[12]=V3.x; v[13]=V3.y; v[14]=V3.z; v[15]=V3.w;
          v[16]=V4.x; v[17]=V4.y; v[18]=V4.z; v[19]=V4.w;
          v[20]=V5.x; v[21]=V5.y; v[22]=V5.z; v[23]=V5.w;
          float sv = ((v[0] + v[1]) + (v[2] + v[3])) +
                     ((v[4] + v[5]) + (v[6] + v[7])) + v[8];
          hwr[0] = sv;
#pragma unroll
          for (int h = 1; h < TH; ++h) {
            sv += v[h + 8] - v[h - 1];
            hwr[h * HHS] = sv;
          }
        }
      }

      bar_lgkm();  // B

      // ---- I2: P4(s) + store slice m+1 + prefetch m+2 ----
      float hv0 = 0.f, hv1 = 0.f, hv2 = 0.f, hv3 = 0.f, hv4 = 0.f;
      if ((unsigned)(g0 + s) < (unsigned)DD) {
        hv0 = hrd[0];
        hv1 = hrd[HCS];
        hv2 = hrd[2 * HCS];
        hv3 = hrd[3 * HCS];
        hv4 = hrd[4 * HCS];
      }
      if (ps0) *(float4*)&(&sbuf[0][0])[la0] = st0;
      if (ps1) *(float4*)&(&sbuf[0][0])[la1] = st1;
      {
        const int gn = g0 + m + 2;
        const bool nv = (m + 2 < NITER) && ((unsigned)gn < (unsigned)DD);
        const long so = (long)gn * HW;
        ps0 = tk0 && nv; if (ps0) st0 = *(const float4*)(gp0 + so);
        ps1 = tk1 && nv; if (ps1) st1 = *(const float4*)(gp1 + so);
      }

      run0 += hv0 - ring[jj][0]; ring[jj][0] = hv0;
      run1 += hv1 - ring[jj][1]; ring[jj][1] = hv1;
      run2 += hv2 - ring[jj][2]; ring[jj][2] = hv2;
      run3 += hv3 - ring[jj][3]; ring[jj][3] = hv3;
      run4 += hv4 - ring[jj][4]; ring[jj][4] = hv4;

      if (s >= 8) {
        const int d = dc0 + (s - 8);
        if (d < DD) {                   // block-uniform tail guard
          float cross = fmaf(-run0 * INV_WS, run1, run4);
          float xv = fmaxf(fmaf(-run0 * INV_WS, run0, run2), EPS);
          float yv = fmaxf(fmaf(-run1 * INV_WS, run1, run3), EPS);
          acc += (cross * cross) * __builtin_amdgcn_rcpf(xv * yv);
        }
      }

      bar_lgkm();  // C
    }
  }

  // ---- block reduction ----
#pragma unroll
  for (int o = 32; o > 0; o >>= 1) acc += __shfl_down(acc, o);
  if ((t & 63) == 0) red[t >> 6] = acc;
  __syncthreads();
  if (t == 0) {
    int bid = (bz * HT + blockIdx.y) * WT + blockIdx.x;
    partials[bid] = (red[0] + red[1]) + (red[2] + red[3]);
  }
}

__global__ void __launch_bounds__(256) k_finalize(
    const float* __restrict__ partials, float* __restrict__ out)
{
  __shared__ double red[256];
  double s = 0.0;
  for (int i = threadIdx.x; i < NBLK; i += 256) s += (double)partials[i];
  red[threadIdx.x] = s;
  __syncthreads();
  for (int o = 128; o > 0; o >>= 1) {
    if (threadIdx.x < o) red[threadIdx.x] += red[threadIdx.x + o];
    __syncthreads();
  }
  if (threadIdx.x == 0) {
    const double Nvox = (double)BB * DD * HH * WW;
    out[0] = (float)(-red[0] / Nvox);
  }
}

extern "C" void kernel_launch(void* const* d_in, const int* in_sizes, int n_in,
                              void* d_out, int out_size, void* d_ws, size_t ws_size,
                              hipStream_t stream) {
  (void)in_sizes; (void)n_in; (void)out_size; (void)ws_size;
  const float* x = (const float*)d_in[0];
  const float* y = (const float*)d_in[1];
  float* out = (float*)d_out;
  float* partials = (float*)d_ws;

  dim3 grid(WT, HT, BB * NCH);
  k_lncc<<<grid, 256, 0, stream>>>(x, y, partials);
  k_finalize<<<1, 256, 0, stream>>>(partials, out);
}